// Round 8
// baseline (438.619 us; speedup 1.0000x reference)
//
#include <hip/hip_runtime.h>
#include <hip/hip_bf16.h>

#define B_ 16
#define L_ 8192
#define F_ 512
#define I_ 512
#define A_ 256
#define LT 128
#define NCH 16   // 512 / 32

typedef __attribute__((ext_vector_type(4))) float f32x4;
typedef __attribute__((ext_vector_type(8))) __bf16 bf16x8;

__device__ __forceinline__ unsigned short f2bf(float f) {
  return __builtin_bit_cast(unsigned short, (__bf16)f);  // RNE
}

// ---------------- K0: W_feat fp32 -> bf16 (layout preserved [A][F]) -------
__global__ void k_wcvt(const float* __restrict__ W, unsigned short* __restrict__ wb) {
  int i = blockIdx.x * 256 + threadIdx.x;     // 32768 float4s
  float4 v = ((const float4*)W)[i];
  ushort4 d;
  d.x = f2bf(v.x); d.y = f2bf(v.y); d.z = f2bf(v.z); d.w = f2bf(v.w);
  ((ushort4*)wb)[i] = d;
}

// ---------------- K1: proj_inp = z @ W_inp^T + b_inp ----------------------
__global__ void k_proj(const float* __restrict__ z, const float* __restrict__ Wi,
                       const float* __restrict__ bi, float* __restrict__ proj) {
  __shared__ float zb[I_];
  const int b = blockIdx.x, t = threadIdx.x;  // 256 threads, t = a
  zb[t] = z[b * I_ + t];
  zb[t + 256] = z[b * I_ + t + 256];
  __syncthreads();
  const float4* w4 = (const float4*)(Wi + t * I_);
  float s = bi[t];
  for (int i = 0; i < I_ / 4; ++i) {
    float4 w = w4[i];
    s += w.x * zb[4*i] + w.y * zb[4*i+1] + w.z * zb[4*i+2] + w.w * zb[4*i+3];
  }
  proj[b * A_ + t] = s;
}

// ---------------- K2: main fused GEMM + scores + softmax partials + Nf ----
// grid 1024 = b(16) x ltile(64); 512 threads = 8 waves (4 in a, 2 in l)
__global__ __launch_bounds__(512, 2) void k_main(
    const float* __restrict__ feat,            // [B][F][L]
    const unsigned short* __restrict__ wbf,    // [A][F] bf16
    const float* __restrict__ proj,            // [B][A]
    const float* __restrict__ vatt,            // [A]
    float* __restrict__ scores_ws,             // [B][L]
    float* __restrict__ mz_ws,                 // [1024][2]
    float* __restrict__ nf_ws)                 // [1024][F]
{
  constexpr int PBUF = 131072;
  constexpr int VBUF = 132096;
  constexpr int SPART = 133120;   // 4*128 f32
  constexpr int SBUF = 135168;    // 128 f32
  constexpr int WBUF = 135680;    // 128 f32
  constexpr int MZB  = 136192;    // 4 f32
  constexpr int NFP  = 136208;    // 8*512 f32
  __shared__ __align__(16) unsigned char smem[136208 + 16384];

  const int tid  = threadIdx.x;
  const int lane = tid & 63;
  const int wid  = tid >> 6;
  const int wm   = wid >> 1;      // 0..3  (a dim, 64 rows each)
  const int wn   = wid & 1;       // 0..1  (l dim, 64 cols each)
  const int bx   = blockIdx.x;
  const int b    = bx >> 6;
  const int l0   = (bx & 63) * LT;

  const float* fb = feat + (size_t)b * F_ * L_;

  float* pbufF  = (float*)(smem + PBUF);
  float* vbufF  = (float*)(smem + VBUF);
  float* spartF = (float*)(smem + SPART);
  float* sbufF  = (float*)(smem + SBUF);
  float* wbufF  = (float*)(smem + WBUF);
  float* mzF    = (float*)(smem + MZB);
  float* nfpF   = (float*)(smem + NFP);

  if (tid < A_) { pbufF[tid] = proj[b * A_ + tid]; vbufF[tid] = vatt[tid]; }

  // feat chunk c: k rows f = 32c + 4*wid + j (j=0..3), cols l0 + 2*lane + {0,1}
  auto load_feat = [&](int c, float2* r) {
    const float* p = fb + (size_t)(32 * c + 4 * wid) * L_ + l0 + 2 * lane;
    r[0] = *(const float2*)(p);
    r[1] = *(const float2*)(p + L_);
    r[2] = *(const float2*)(p + 2 * L_);
    r[3] = *(const float2*)(p + 3 * L_);
  };
  // LDS element (l,k): byte = l*1024 + (((k>>2) ^ (((l>>1)&31)<<1))<<3) + (k&3)*2
  auto write_feat = [&](int c, const float2* r) {
    const int s = 8 * c + wid;   // s = k>>2, 0..127
    #pragma unroll
    for (int h = 0; h < 2; ++h) {
      const int l = 2 * lane + h;
      ushort4 d;
      d.x = f2bf(h ? r[0].y : r[0].x);
      d.y = f2bf(h ? r[1].y : r[1].x);
      d.z = f2bf(h ? r[2].y : r[2].x);
      d.w = f2bf(h ? r[3].y : r[3].x);
      *(ushort4*)(smem + (l << 10) + ((s ^ (((l >> 1) & 31) << 1)) << 3)) = d;
    }
  };
  // W A-fragments straight from global bf16 (L2-resident)
  auto load_wf = [&](int c, bf16x8* wf) {
    const unsigned short* p = wbf + (64 * wm + (lane & 15)) * F_ + 32 * c + ((lane >> 4) << 3);
    wf[0] = *(const bf16x8*)(p);
    wf[1] = *(const bf16x8*)(p + 16 * F_);
    wf[2] = *(const bf16x8*)(p + 32 * F_);
    wf[3] = *(const bf16x8*)(p + 48 * F_);
  };

  f32x4 acc[4][4];
  #pragma unroll
  for (int i = 0; i < 4; ++i)
    #pragma unroll
    for (int j = 0; j < 4; ++j) acc[i][j] = (f32x4)0.0f;

  float2 fra[4], frb[4];
  bf16x8 wfc[4], wfn[4];

  load_feat(0, fra);
  load_feat(1, frb);
  load_wf(0, wfc);
  write_feat(0, fra);
  write_feat(1, frb);
  load_feat(2, fra);
  __syncthreads();

  for (int c = 0; c < NCH; ++c) {
    if (c + 3 < NCH) load_feat(c + 3, frb);
    if (c + 1 < NCH) load_wf(c + 1, wfn);
    const int lcol = 64 * wn + (lane & 15);
    const int og = 4 * c + (lane >> 4);
    #pragma unroll
    for (int fn = 0; fn < 4; ++fn) {
      const int l = lcol + 16 * fn;
      bf16x8 bfr = *(const bf16x8*)(smem + (l << 10) + ((og ^ ((l >> 1) & 31)) << 4));
      #pragma unroll
      for (int fm = 0; fm < 4; ++fm)
        acc[fm][fn] = __builtin_amdgcn_mfma_f32_16x16x32_bf16(wfc[fm], bfr, acc[fm][fn], 0, 0, 0);
    }
    if (c + 2 < NCH) write_feat(c + 2, fra);
    __syncthreads();
    #pragma unroll
    for (int q = 0; q < 4; ++q) { fra[q] = frb[q]; wfc[q] = wfn[q]; }
  }

  // ---- epilogue: scores = sum_a relu(acc + p[a]) * v[a] ----
  float ts[4] = {0.f, 0.f, 0.f, 0.f};
  {
    const int rb = 64 * wm + ((lane >> 4) << 2);
    #pragma unroll
    for (int fm = 0; fm < 4; ++fm)
      #pragma unroll
      for (int jj = 0; jj < 4; ++jj) {
        const int a = rb + 16 * fm + jj;
        const float pa = pbufF[a];
        const float va = vbufF[a];
        #pragma unroll
        for (int fn = 0; fn < 4; ++fn) {
          float x = acc[fm][fn][jj] + pa;
          x = fmaxf(x, 0.0f);
          ts[fn] = fmaf(x, va, ts[fn]);
        }
      }
  }
  #pragma unroll
  for (int fn = 0; fn < 4; ++fn) {
    ts[fn] += __shfl_xor(ts[fn], 16);
    ts[fn] += __shfl_xor(ts[fn], 32);
  }
  if (lane < 16) {
    #pragma unroll
    for (int fn = 0; fn < 4; ++fn)
      spartF[wm * 128 + 64 * wn + 16 * fn + lane] = ts[fn];
  }
  __syncthreads();
  if (tid < 128) {
    float s = spartF[tid] + spartF[128 + tid] + spartF[256 + tid] + spartF[384 + tid];
    scores_ws[b * L_ + l0 + tid] = s;
    sbufF[tid] = s;
  }
  __syncthreads();
  if (tid < 64) {
    float m = fmaxf(sbufF[tid], sbufF[tid + 64]);
    #pragma unroll
    for (int d = 32; d > 0; d >>= 1) m = fmaxf(m, __shfl_xor(m, d));
    if (tid == 0) mzF[0] = m;
  }
  __syncthreads();
  const float Mb = mzF[0];
  if (tid < 128) wbufF[tid] = expf(sbufF[tid] - Mb);
  __syncthreads();
  if (tid < 64) {
    float zz = wbufF[tid] + wbufF[tid + 64];
    #pragma unroll
    for (int d = 32; d > 0; d >>= 1) zz += __shfl_xor(zz, d);
    if (tid == 0) mzF[1] = zz;
  }
  // ---- Nf partial = sum_l feat_bf16[f][l] * w[l], reusing resident tile ----
  {
    const int fo = tid & 63;     // f-octet
    const int sl = tid >> 6;     // l slice of 16
    float na[8];
    #pragma unroll
    for (int e = 0; e < 8; ++e) na[e] = 0.f;
    for (int li = 0; li < 16; ++li) {
      const int l = sl * 16 + li;
      const float w = wbufF[l];
      bf16x8 fv = *(const bf16x8*)(smem + (l << 10) + ((fo ^ ((l >> 1) & 31)) << 4));
      #pragma unroll
      for (int e = 0; e < 8; ++e) na[e] = fmaf((float)fv[e], w, na[e]);
    }
    #pragma unroll
    for (int e = 0; e < 8; ++e) nfpF[sl * 512 + fo * 8 + e] = na[e];
  }
  __syncthreads();
  {
    float v = 0.f;
    #pragma unroll
    for (int s2 = 0; s2 < 8; ++s2) v += nfpF[s2 * 512 + tid];
    nf_ws[(size_t)bx * 512 + tid] = v;
  }
  if (tid == 0) { mz_ws[bx * 2] = Mb; mz_ws[bx * 2 + 1] = mzF[1]; }
}

// ---------------- K3: combine partials, write ctx + alpha -----------------
__global__ void k_final(const float* __restrict__ scores_ws,
                        const float* __restrict__ mz_ws,
                        const float* __restrict__ nf_ws,
                        float* __restrict__ out) {
  __shared__ float scl[64];
  __shared__ float MZ[2];
  const int b = blockIdx.x, t = threadIdx.x;  // 256 threads
  if (t < 64) {
    float m = mz_ws[(b * 64 + t) * 2];
    float z = mz_ws[(b * 64 + t) * 2 + 1];
    float M = m;
    #pragma unroll
    for (int d = 32; d > 0; d >>= 1) M = fmaxf(M, __shfl_xor(M, d));
    float sc = expf(m - M);
    float zz = z * sc;
    #pragma unroll
    for (int d = 32; d > 0; d >>= 1) zz += __shfl_xor(zz, d);
    scl[t] = sc;
    if (t == 0) { MZ[0] = M; MZ[1] = zz; }
  }
  __syncthreads();
  const float M = MZ[0];
  const float invZ = 1.0f / MZ[1];
  for (int f = t; f < F_; f += 256) {
    float a = 0.f;
    for (int i = 0; i < 64; ++i)
      a = fmaf(nf_ws[((size_t)b * 64 + i) * 512 + f], scl[i], a);
    out[b * F_ + f] = a * invZ;
  }
  const float* sr = scores_ws + (size_t)b * L_;
  float* ao = out + B_ * F_ + (size_t)b * L_;
  for (int l = t; l < L_; l += 256) {
    ao[l] = expf(sr[l] - M) * invZ;
  }
}

extern "C" void kernel_launch(void* const* d_in, const int* in_sizes, int n_in,
                              void* d_out, int out_size, void* d_ws, size_t ws_size,
                              hipStream_t stream) {
  const float* z    = (const float*)d_in[0];
  const float* feat = (const float*)d_in[1];
  const float* Wf   = (const float*)d_in[2];
  const float* Wi   = (const float*)d_in[3];
  const float* bi   = (const float*)d_in[4];
  const float* va   = (const float*)d_in[5];
  float* out = (float*)d_out;
  char* ws = (char*)d_ws;

  float* proj    = (float*)(ws + 0);            // 4096 f32
  float* scores  = (float*)(ws + 16384);        // 131072 f32
  float* mz      = (float*)(ws + 540672);       // 2048 f32
  float* nf      = (float*)(ws + 548864);       // 524288 f32
  unsigned short* wbf = (unsigned short*)(ws + 2646016);  // 131072 bf16

  k_wcvt<<<128, 256, 0, stream>>>(Wf, wbf);
  k_proj<<<16, 256, 0, stream>>>(z, Wi, bi, proj);
  k_main<<<1024, 512, 0, stream>>>(feat, wbf, proj, va, scores, mz, nf);
  k_final<<<16, 256, 0, stream>>>(scores, mz, nf, out);
}